// Round 12
// baseline (47.833 us; speedup 1.0000x reference)
//
#include <hip/hip_runtime.h>

typedef __attribute__((ext_vector_type(8))) short bf16x8;
typedef __attribute__((ext_vector_type(4))) float f32x4;

constexpr int TN = 8192;   // tokens
constexpr int DN = 4096;   // model dim
constexpr int EN = 64;     // experts

constexpr int BM = 64;         // rows per block (4 row-halves of 16)
constexpr int NS = DN / 32;    // 128 MFMA K32 slots total

__device__ __forceinline__ unsigned short f2bf(float f) {  // RNE f32->bf16
    unsigned u = __builtin_bit_cast(unsigned, f);
    u += 0x7FFFu + ((u >> 16) & 1u);
    return (unsigned short)(u >> 16);
}
__device__ __forceinline__ float bf2f(unsigned short h) {
    unsigned u = ((unsigned)h) << 16;
    return __builtin_bit_cast(float, u);
}

// Kernel 0: split wg into hi/lo bf16 planes in MFMA-fragment order:
// BF[p][s][et][lane*8+j] = plane_p( wg[et*16+(lane&15)][s*32+(lane>>4)*8+j] )
// so a wave's B-fragment load in the GEMM is base + lane*16B (1KB coalesced).
__global__ __launch_bounds__(256)
void wg_frag_kernel(const float* __restrict__ wg, unsigned short* __restrict__ BF) {
    const int gid = blockIdx.x * 256 + threadIdx.x;  // 65536 items
    const int l  = gid & 63;
    const int et = (gid >> 6) & 3;
    const int s  = (gid >> 8) & (NS - 1);
    const int p  = gid >> 15;
    const int e  = et * 16 + (l & 15);
    const int k  = s * 32 + (l >> 4) * 8;

    const float* src = wg + (size_t)e * DN + k;
    float4 v0 = *reinterpret_cast<const float4*>(src);
    float4 v1 = *reinterpret_cast<const float4*>(src + 4);
    float f[8] = {v0.x, v0.y, v0.z, v0.w, v1.x, v1.y, v1.z, v1.w};
    unsigned short o[8];
#pragma unroll
    for (int j = 0; j < 8; ++j) {
        unsigned short h = f2bf(f[j]);
        o[j] = p ? f2bf(f[j] - bf2f(h)) : h;
    }
    unsigned short* dst = BF + (((size_t)p * NS + s) * 4 + et) * 512 + (size_t)l * 8;
    *reinterpret_cast<ushort4*>(dst)     = make_ushort4(o[0], o[1], o[2], o[3]);
    *reinterpret_cast<ushort4*>(dst + 4) = make_ushort4(o[4], o[5], o[6], o[7]);
}

// Kernel 1: barrier-free direct-gather split-bf16 MFMA GEMM, K-split partials.
// Grid = 128 row-tiles x KSPLIT K-chunks (KSPLIT=4 -> 512 blocks = 2/CU,
// 8 waves/CU). 256 threads = 4 INDEPENDENT waves; wave w owns K32 slots
// ks*32 + t*4 + w and computes FOUR 16-row halves (64 rows) per B-load --
// halves per-block vector-memory bytes vs BM=32 (the measured ~20B/cyc/CU
// delivery limit). A-fragments loaded per-lane straight from global x
// (lanes fr..fr+48 cover one 128B line per row) and split hi/lo bf16
// in-register. A and B depth-2 ping-pong, compute-then-load (WAR-safe).
// Note: ks = bid%4 with round-robin XCD dispatch pins one 256KB B-quarter
// per XCD's L2.
template <int KSPLIT>
__global__ __launch_bounds__(256, 2)
void gate_gemm_kernel(const float* __restrict__ x,
                      const unsigned short* __restrict__ BF,
                      float* __restrict__ part) {
    constexpr int SLOTS = NS / KSPLIT;   // K32 slots per block
    constexpr int NTW   = SLOTS / 4;     // phases per wave

    __shared__ float L[2][BM][68];       // 34816 B; two-stage reduce buffer

    const int tid  = threadIdx.x;
    const int lane = tid & 63;
    const int w    = tid >> 6;           // wave 0..3
    const int rt   = blockIdx.x / KSPLIT;
    const int ks   = blockIdx.x % KSPLIT;
    const int r0   = rt * BM;
    const int sbase = ks * SLOTS;

    const int fr  = lane & 15;           // fragment row (A) / expert col (B)
    const int fko = (lane >> 4) * 8;     // fragment k offset within K=32

    const float* xa = x + (size_t)(r0 + fr) * DN + fko;

    f32x4 acc[4][4] = {};                // [row-half][expert-tile]

    float4 XA[2][4][2];                  // depth-2 A fp32 ([set][rh][2x float4])
    bf16x8 Bq[2][8];                     // depth-2 B ([set][et]=hi, [set][4+et]=lo)

    auto loadA = [&](int set, int t) {
        const int s = sbase + t * 4 + w;
        const float* p = xa + (size_t)s * 32;
#pragma unroll
        for (int rh = 0; rh < 4; ++rh) {
            const float* pr = p + (size_t)rh * 16 * DN;
            XA[set][rh][0] = *reinterpret_cast<const float4*>(pr);
            XA[set][rh][1] = *reinterpret_cast<const float4*>(pr + 4);
        }
    };
    auto loadB = [&](int set, int t) {
        const int s = sbase + t * 4 + w;
        const unsigned short* bp = BF + (size_t)s * 2048 + (size_t)lane * 8;
#pragma unroll
        for (int et = 0; et < 4; ++et)
            Bq[set][et] = *reinterpret_cast<const bf16x8*>(bp + et * 512);
#pragma unroll
        for (int et = 0; et < 4; ++et)
            Bq[set][4 + et] = *reinterpret_cast<const bf16x8*>(bp + (size_t)NS * 2048 + et * 512);
    };
    auto compute = [&](int set) {
#pragma unroll
        for (int rh = 0; rh < 4; ++rh) {
            float f[8] = {XA[set][rh][0].x, XA[set][rh][0].y,
                          XA[set][rh][0].z, XA[set][rh][0].w,
                          XA[set][rh][1].x, XA[set][rh][1].y,
                          XA[set][rh][1].z, XA[set][rh][1].w};
            bf16x8 ah, al;
#pragma unroll
            for (int j = 0; j < 8; ++j) {
                unsigned short hh = f2bf(f[j]);
                ah[j] = (short)hh;
                al[j] = (short)f2bf(f[j] - bf2f(hh));
            }
#pragma unroll
            for (int et = 0; et < 4; ++et) {
                acc[rh][et] = __builtin_amdgcn_mfma_f32_16x16x32_bf16(ah, Bq[set][et],     acc[rh][et], 0, 0, 0);
                acc[rh][et] = __builtin_amdgcn_mfma_f32_16x16x32_bf16(al, Bq[set][et],     acc[rh][et], 0, 0, 0);
                acc[rh][et] = __builtin_amdgcn_mfma_f32_16x16x32_bf16(ah, Bq[set][4 + et], acc[rh][et], 0, 0, 0);
                acc[rh][et] = __builtin_amdgcn_mfma_f32_16x16x32_bf16(al, Bq[set][4 + et], acc[rh][et], 0, 0, 0);
            }
        }
    };

    // barrier-free depth-2 pipeline; fully unrolled so set indices are static
    loadA(0, 0); loadB(0, 0);
    loadA(1, 1); loadB(1, 1);
#pragma unroll
    for (int t = 0; t < NTW; ++t) {
        compute(t & 1);
        if (t + 2 < NTW) { loadA(t & 1, t + 2); loadB(t & 1, t + 2); }
        asm volatile("" ::: "memory");   // pin per-phase issue order
    }

    // two-stage in-place LDS reduction across the 4 waves (L is 2 slots):
    // waves 0,1 overwrite slot w; waves 2,3 add into slot w-2.
    // C/D layout: col = lane&15, row = (lane>>4)*4 + reg  [m89]
    if (w < 2) {
#pragma unroll
        for (int rh = 0; rh < 4; ++rh)
#pragma unroll
            for (int et = 0; et < 4; ++et)
#pragma unroll
                for (int r = 0; r < 4; ++r)
                    L[w][rh * 16 + (lane >> 4) * 4 + r][et * 16 + fr] = acc[rh][et][r];
    }
    __syncthreads();
    if (w >= 2) {
#pragma unroll
        for (int rh = 0; rh < 4; ++rh)
#pragma unroll
            for (int et = 0; et < 4; ++et)
#pragma unroll
                for (int r = 0; r < 4; ++r)
                    L[w - 2][rh * 16 + (lane >> 4) * 4 + r][et * 16 + fr] += acc[rh][et][r];
    }
    __syncthreads();

    {
        const int row = tid >> 2;        // 0..63
        const int eg  = tid & 3;         // 16 experts each
        float v[16];
#pragma unroll
        for (int j = 0; j < 16; ++j)
            v[j] = L[0][row][eg * 16 + j] + L[1][row][eg * 16 + j];
        float* dst = part + ((size_t)ks * TN + r0 + row) * EN + eg * 16;
#pragma unroll
        for (int j = 0; j < 16; j += 4)
            *reinterpret_cast<float4*>(&dst[j]) = make_float4(v[j], v[j+1], v[j+2], v[j+3]);
    }
}

// Kernel 2: sum KSPLIT partials, top-1 softmax per row.
// out[0..TN) = argmax index (as float), out[TN..2TN) = max gate = 1/sumexp.
template <int NSPLIT>
__global__ __launch_bounds__(256)
void top1_softmax_kernel(const float* __restrict__ part, float* __restrict__ out) {
    const int row = blockIdx.x * blockDim.x + threadIdx.x;
    if (row >= TN) return;

    float v[EN];
#pragma unroll
    for (int i = 0; i < EN / 4; ++i) {
        float4 s = *reinterpret_cast<const float4*>(&part[(size_t)row * EN + i * 4]);
#pragma unroll
        for (int h = 1; h < NSPLIT; ++h) {
            float4 t = *reinterpret_cast<const float4*>(
                &part[((size_t)h * TN + row) * EN + i * 4]);
            s.x += t.x; s.y += t.y; s.z += t.z; s.w += t.w;
        }
        v[i * 4 + 0] = s.x; v[i * 4 + 1] = s.y;
        v[i * 4 + 2] = s.z; v[i * 4 + 3] = s.w;
    }

    float m = v[0];
    int idx = 0;
#pragma unroll
    for (int e = 1; e < EN; ++e)
        if (v[e] > m) { m = v[e]; idx = e; }  // strict >: first occurrence = jnp.argmax
    float s = 0.0f;
#pragma unroll
    for (int e = 0; e < EN; ++e) s += __expf(v[e] - m);

    out[row]      = (float)idx;
    out[TN + row] = 1.0f / s;
}

extern "C" void kernel_launch(void* const* d_in, const int* in_sizes, int n_in,
                              void* d_out, int out_size, void* d_ws, size_t ws_size,
                              hipStream_t stream) {
    const float* x  = (const float*)d_in[0];
    const float* wg = (const float*)d_in[1];
    float* out = (float*)d_out;

    constexpr size_t BF_BYTES = (size_t)2 * NS * 4 * 512 * 2;  // 1 MB
    unsigned short* BF = (unsigned short*)d_ws;
    float* part = (float*)((char*)d_ws + BF_BYTES);

    wg_frag_kernel<<<dim3(256), dim3(256), 0, stream>>>(wg, BF);

    const size_t need4 = BF_BYTES + (size_t)4 * TN * EN * sizeof(float);  // 9 MB
    const size_t need2 = BF_BYTES + (size_t)2 * TN * EN * sizeof(float);  // 5 MB
    if (ws_size >= need4) {
        gate_gemm_kernel<4><<<dim3(128 * 4), dim3(256), 0, stream>>>(x, BF, part);
        top1_softmax_kernel<4><<<dim3(TN / 256), dim3(256), 0, stream>>>(part, out);
    } else if (ws_size >= need2) {
        gate_gemm_kernel<2><<<dim3(128 * 2), dim3(256), 0, stream>>>(x, BF, part);
        top1_softmax_kernel<2><<<dim3(TN / 256), dim3(256), 0, stream>>>(part, out);
    } else {
        gate_gemm_kernel<1><<<dim3(128), dim3(256), 0, stream>>>(x, BF, part);
        top1_softmax_kernel<1><<<dim3(TN / 256), dim3(256), 0, stream>>>(part, out);
    }
}

// Round 13
// 38.937 us; speedup vs baseline: 1.2285x; 1.2285x over previous
//
#include <hip/hip_runtime.h>

typedef __attribute__((ext_vector_type(8))) short bf16x8;
typedef __attribute__((ext_vector_type(4))) float f32x4;
typedef __attribute__((ext_vector_type(4))) unsigned u32x4;

constexpr int TN = 8192;   // tokens
constexpr int DN = 4096;   // model dim
constexpr int EN = 64;     // experts

constexpr int BM = 32;         // rows per block
constexpr int NS = DN / 32;    // 128 MFMA K32 slots
constexpr int NT = 16;         // slots per wave (128 / 8 waves)

__device__ __forceinline__ unsigned short f2bf(float f) {  // RNE f32->bf16
    unsigned u = __builtin_bit_cast(unsigned, f);
    u += 0x7FFFu + ((u >> 16) & 1u);
    return (unsigned short)(u >> 16);
}
__device__ __forceinline__ float bf2f(unsigned short h) {
    unsigned u = ((unsigned)h) << 16;
    return __builtin_bit_cast(float, u);
}

// RNE hi/lo bf16 split of a pair of f32, packed as (f1<<16|f0) words.
// hi: RNE-rounded top-16 via bit math, packed with one v_perm_b32.
// lo: RNE of (f - hi), packed the same way. ~14 VALU ops per pair.
__device__ __forceinline__ void split_pair(float f0, float f1,
                                           unsigned& hi, unsigned& lo) {
    unsigned u0 = __builtin_bit_cast(unsigned, f0);
    unsigned u1 = __builtin_bit_cast(unsigned, f1);
    unsigned r0 = u0 + 0x7FFFu + ((u0 >> 16) & 1u);
    unsigned r1 = u1 + 0x7FFFu + ((u1 >> 16) & 1u);
    hi = __builtin_amdgcn_perm(r1, r0, 0x07060302u);  // {r1.hi16, r0.hi16}
    float h0 = __builtin_bit_cast(float, r0 & 0xFFFF0000u);
    float h1 = __builtin_bit_cast(float, r1 & 0xFFFF0000u);
    unsigned v0 = __builtin_bit_cast(unsigned, f0 - h0);
    unsigned v1 = __builtin_bit_cast(unsigned, f1 - h1);
    unsigned s0 = v0 + 0x7FFFu + ((v0 >> 16) & 1u);
    unsigned s1 = v1 + 0x7FFFu + ((v1 >> 16) & 1u);
    lo = __builtin_amdgcn_perm(s1, s0, 0x07060302u);
}

// Kernel 0: split wg into hi/lo bf16 planes in MFMA-fragment order:
// BF[p][s][et][lane*8+j] = plane_p( wg[et*16+(lane&15)][s*32+(lane>>4)*8+j] )
// so a wave's B-fragment load in the GEMM is base + lane*16B (1KB coalesced).
__global__ __launch_bounds__(256)
void wg_frag_kernel(const float* __restrict__ wg, unsigned short* __restrict__ BF) {
    const int gid = blockIdx.x * 256 + threadIdx.x;  // 65536 items
    const int l  = gid & 63;
    const int et = (gid >> 6) & 3;
    const int s  = (gid >> 8) & (NS - 1);
    const int p  = gid >> 15;
    const int e  = et * 16 + (l & 15);
    const int k  = s * 32 + (l >> 4) * 8;

    const float* src = wg + (size_t)e * DN + k;
    float4 v0 = *reinterpret_cast<const float4*>(src);
    float4 v1 = *reinterpret_cast<const float4*>(src + 4);
    float f[8] = {v0.x, v0.y, v0.z, v0.w, v1.x, v1.y, v1.z, v1.w};
    unsigned short o[8];
#pragma unroll
    for (int j = 0; j < 8; ++j) {
        unsigned short h = f2bf(f[j]);
        o[j] = p ? f2bf(f[j] - bf2f(h)) : h;
    }
    unsigned short* dst = BF + (((size_t)p * NS + s) * 4 + et) * 512 + (size_t)l * 8;
    *reinterpret_cast<ushort4*>(dst)     = make_ushort4(o[0], o[1], o[2], o[3]);
    *reinterpret_cast<ushort4*>(dst + 4) = make_ushort4(o[4], o[5], o[6], o[7]);
}

// Kernel 1: barrier-free direct-gather split-bf16 MFMA GEMM + fused top-1.
// Grid = 256 blocks (1/CU), 512 threads = 8 INDEPENDENT waves. Wave w =
// (kq=w&3, kh=w>>2) owns K32 slots kh*64+t*4+kq and computes both 16-row
// halves (B regs shared). A-fragments gathered per-lane straight from x.
// Pipeline (vmcnt-FIFO aware, m135): phase t = { compute(t); loadB(t+2);
// loadA(t+3) } -- B issued BEFORE A each phase, so compute's wait for
// B(t) (the youngest needed) drains only loads >=2 phases old: B slack =
// 2 phases (~1000cyc >= L2 ~300), A slack = 3 phases (~1500 >= HBM ~900),
// and no wait ever drains a load younger than its own need.
// MFMA order is product-outer: same-accumulator reuse distance = 8.
__global__ __launch_bounds__(512, 2)
void gate_fused_kernel(const float* __restrict__ x,
                       const unsigned short* __restrict__ BF,
                       float* __restrict__ out) {
    __shared__ float L[8][BM][68];      // 69632 B; per-wave partial logits

    const int tid  = threadIdx.x;
    const int lane = tid & 63;
    const int w    = tid >> 6;          // wave 0..7
    const int kq   = w & 3;
    const int kh   = w >> 2;
    const int r0   = blockIdx.x * BM;

    const int fr  = lane & 15;          // fragment row (A) / expert col (B)
    const int fko = (lane >> 4) * 8;    // fragment k offset within K=32

    const float* xa = x + (size_t)(r0 + fr) * DN + fko;

    f32x4 acc[2][4] = {};               // [row-half][expert-tile]

    float4 XA[3][2][2];                 // depth-3 A fp32 ([set][rh][2x float4])
    bf16x8 Bq[2][8];                    // depth-2 B ([set][et]=hi, [set][4+et]=lo)

    auto loadA = [&](int set, int t) {
        const int s = kh * 64 + t * 4 + kq;
        const float* p = xa + (size_t)s * 32;
#pragma unroll
        for (int rh = 0; rh < 2; ++rh) {
            const float* pr = p + (size_t)rh * 16 * DN;
            XA[set][rh][0] = *reinterpret_cast<const float4*>(pr);
            XA[set][rh][1] = *reinterpret_cast<const float4*>(pr + 4);
        }
    };
    auto loadB = [&](int set, int t) {
        const int s = kh * 64 + t * 4 + kq;
        const unsigned short* bp = BF + (size_t)s * 2048 + (size_t)lane * 8;
#pragma unroll
        for (int et = 0; et < 4; ++et)
            Bq[set][et] = *reinterpret_cast<const bf16x8*>(bp + et * 512);
#pragma unroll
        for (int et = 0; et < 4; ++et)
            Bq[set][4 + et] = *reinterpret_cast<const bf16x8*>(bp + (size_t)NS * 2048 + et * 512);
    };
    auto compute = [&](int aset, int bset) {
        bf16x8 ah[2], al[2];
#pragma unroll
        for (int rh = 0; rh < 2; ++rh) {
            float f[8] = {XA[aset][rh][0].x, XA[aset][rh][0].y,
                          XA[aset][rh][0].z, XA[aset][rh][0].w,
                          XA[aset][rh][1].x, XA[aset][rh][1].y,
                          XA[aset][rh][1].z, XA[aset][rh][1].w};
            u32x4 uh, ul;
#pragma unroll
            for (int q = 0; q < 4; ++q) {
                unsigned hw, lw;
                split_pair(f[2 * q], f[2 * q + 1], hw, lw);
                uh[q] = hw; ul[q] = lw;
            }
            ah[rh] = __builtin_bit_cast(bf16x8, uh);
            al[rh] = __builtin_bit_cast(bf16x8, ul);
        }
        // product-outer order: 8 independent acc chains between reuses
#pragma unroll
        for (int et = 0; et < 4; ++et)
#pragma unroll
            for (int rh = 0; rh < 2; ++rh)
                acc[rh][et] = __builtin_amdgcn_mfma_f32_16x16x32_bf16(ah[rh], Bq[bset][et], acc[rh][et], 0, 0, 0);
#pragma unroll
        for (int et = 0; et < 4; ++et)
#pragma unroll
            for (int rh = 0; rh < 2; ++rh)
                acc[rh][et] = __builtin_amdgcn_mfma_f32_16x16x32_bf16(al[rh], Bq[bset][et], acc[rh][et], 0, 0, 0);
#pragma unroll
        for (int et = 0; et < 4; ++et)
#pragma unroll
            for (int rh = 0; rh < 2; ++rh)
                acc[rh][et] = __builtin_amdgcn_mfma_f32_16x16x32_bf16(ah[rh], Bq[bset][4 + et], acc[rh][et], 0, 0, 0);
#pragma unroll
        for (int et = 0; et < 4; ++et)
#pragma unroll
            for (int rh = 0; rh < 2; ++rh)
                acc[rh][et] = __builtin_amdgcn_mfma_f32_16x16x32_bf16(al[rh], Bq[bset][4 + et], acc[rh][et], 0, 0, 0);
    };

    // prologue FIFO: B(0), A(0), B(1), A(1), A(2) -- compute(0)'s wait for
    // A(0) drains only B(0),A(0); B(1)/A(1)/A(2) stay in flight.
    loadB(0, 0);
    loadA(0, 0);
    loadB(1, 1);
    loadA(1, 1);
    loadA(2, 2);
#pragma unroll
    for (int t = 0; t < NT; ++t) {      // full unroll: set indices static
        compute(t % 3, t & 1);
        if (t + 2 < NT) loadB(t & 1, t + 2);   // B BEFORE A (FIFO order)
        if (t + 3 < NT) loadA(t % 3, t + 3);
        asm volatile("" ::: "memory");  // pin per-phase issue order
    }

    // epilogue: per-wave partial logits to LDS, then fused top-1 softmax
#pragma unroll
    for (int rh = 0; rh < 2; ++rh)
#pragma unroll
        for (int et = 0; et < 4; ++et)
#pragma unroll
            for (int r = 0; r < 4; ++r)
                // C/D layout: col = lane&15, row = (lane>>4)*4 + reg  [m89]
                L[w][rh * 16 + (lane >> 4) * 4 + r][et * 16 + fr] = acc[rh][et][r];
    __syncthreads();

    {
        const int row = tid >> 4;       // 0..31
        const int eg  = tid & 15;       // 4 experts each
        float v[4];
#pragma unroll
        for (int j = 0; j < 4; ++j) {
            float s = L[0][row][eg * 4 + j];
#pragma unroll
            for (int q = 1; q < 8; ++q) s += L[q][row][eg * 4 + j];
            v[j] = s;
        }
        float m = v[0];
        int idx = eg * 4;
#pragma unroll
        for (int j = 1; j < 4; ++j)
            if (v[j] > m) { m = v[j]; idx = eg * 4 + j; }  // strict >: first occurrence
#pragma unroll
        for (int d = 1; d < 16; d <<= 1) {
            float om = __shfl_xor(m, d);
            int   oi = __shfl_xor(idx, d);
            if (om > m || (om == m && oi < idx)) { m = om; idx = oi; }
        }
        float s = 0.0f;
#pragma unroll
        for (int j = 0; j < 4; ++j) s += __expf(v[j] - m);
#pragma unroll
        for (int d = 1; d < 16; d <<= 1) s += __shfl_xor(s, d);
        if (eg == 0) {
            out[r0 + row]      = (float)idx;     // argmax index
            out[TN + r0 + row] = 1.0f / s;       // max gate = 1/sum(exp(l-lmax))
        }
    }
}

extern "C" void kernel_launch(void* const* d_in, const int* in_sizes, int n_in,
                              void* d_out, int out_size, void* d_ws, size_t ws_size,
                              hipStream_t stream) {
    const float* x  = (const float*)d_in[0];
    const float* wg = (const float*)d_in[1];
    float* out = (float*)d_out;

    unsigned short* BF = (unsigned short*)d_ws;  // 1 MB fragment-ordered hi/lo

    wg_frag_kernel<<<dim3(256), dim3(256), 0, stream>>>(wg, BF);
    gate_fused_kernel<<<dim3(TN / BM), dim3(512), 0, stream>>>(x, BF, out);
}